// Round 6
// baseline (107.297 us; speedup 1.0000x reference)
//
#include <hip/hip_runtime.h>

// RecurrentFixed_PredPrey: 30 iterations of u = tanh(scalar * (drive + w ⊙ N4-stencil(u)))
// on 32768 independent 16x16 images. W_hidden is the fixed grid adjacency -> stencil.
//
// R5 layout: 8 images per wave, 2 packed per lane as float2 (v_pk_*_f32 on CDNA4).
//   lane = (g = lane>>4 slot, r = lane&15 row). Lane holds row r of images
//   {wid*8+2g, wid*8+2g+1} as u[16] float2 (x = image A, y = image B).
//   horizontal neighbors: packed in-register adds (packing is across images -> aligned)
//   vertical neighbors:   DPP row_shr:1/row_shl:1 per 32-bit half; 16-lane DPP row ==
//                         image column span, bound_ctrl zeroes top/bottom edges free.
// Activation (1 trans + packed VALU per pixel):
//   m = pk_fma(w2, ns, drv2)  [w,drv pre-scaled by K = 2*s*log2(e)]
//   e = exp2(-|m|)  in (0,1];  d = 1+e in (1,2]
//   r = 1/d via packed Newton: r0 = 24/17 - (8/17)d; 3x r = r*(2 - d*r)  (f32-exact)
//   u = copysign(1 - 2*e*r, m)
// No LDS, no barriers, no v_rcp: trans count halved vs R4.

namespace {

constexpr int HPIX   = 256;
constexpr int LAYERS = 30;
constexpr int WAVES_PER_BLOCK = 4;
constexpr int IMGS_PER_WAVE   = 8;

typedef float v2f __attribute__((ext_vector_type(2)));

template <int CTRL>
__device__ __forceinline__ float dppf(float x) {
    // old = 0, bound_ctrl=1: out-of-row source lanes yield 0.0f (image edge)
    int r = __builtin_amdgcn_update_dpp(0, __float_as_int(x), CTRL, 0xF, 0xF, true);
    return __int_as_float(r);
}

__device__ __forceinline__ v2f vert_add(v2f ns, v2f uc) {
    ns.x += dppf<0x111>(uc.x) + dppf<0x101>(uc.x);
    ns.y += dppf<0x111>(uc.y) + dppf<0x101>(uc.y);
    return ns;
}

__device__ __forceinline__ v2f act(v2f ns, v2f drv, v2f wc) {
    const v2f m = wc * ns + drv;                      // pk_fma (K-prescaled)
    v2f am;
    am.x = __builtin_fabsf(m.x);
    am.y = __builtin_fabsf(m.y);
    v2f e;
    e.x = __builtin_amdgcn_exp2f(-am.x);              // e in (0,1]
    e.y = __builtin_amdgcn_exp2f(-am.y);
    const v2f d = e + 1.0f;                           // d in (1,2]
    // packed Newton reciprocal of d (seed minimax-linear on [1,2], 3 iterations)
    v2f r = d * (-8.0f / 17.0f) + (24.0f / 17.0f);
    r = r * (2.0f - d * r);
    r = r * (2.0f - d * r);
    r = r * (2.0f - d * r);
    const v2f t = 1.0f - 2.0f * (e * r);              // tanh(|.|) = 1 - 2e/(1+e)
    v2f u;
    u.x = __builtin_copysignf(t.x, m.x);              // v_bfi_b32
    u.y = __builtin_copysignf(t.y, m.y);
    return u;
}

__global__ __launch_bounds__(WAVES_PER_BLOCK * 64)
void pp_kernel(const float* __restrict__ X, const float* __restrict__ pred,
               const float* __restrict__ w, const float* __restrict__ av,
               const float* __restrict__ bias, const float* __restrict__ scalar,
               float* __restrict__ out, int nb)
{
    const int lane = threadIdx.x & 63;
    const int wid  = blockIdx.x * WAVES_PER_BLOCK + (threadIdx.x >> 6);
    const int g    = lane >> 4;                 // image-pair slot 0..3
    const int r    = lane & 15;                 // row 0..15
    const int imgA = wid * IMGS_PER_WAVE + g * 2;
    const bool act0 = (imgA < nb);
    const bool act1 = (imgA + 1 < nb);
    const int iA = act0 ? imgA : 0;             // clamp for safe loads
    const int iB = act1 ? imgA + 1 : 0;
    const size_t baseA = (size_t)iA * HPIX + r * 16;
    const size_t baseB = (size_t)iB * HPIX + r * 16;
    const int    prow  = r * 16;                // per-pixel param row offset

    const float s = scalar[0];
    const float K = 2.0f * s * 1.4426950408889634f;   // 2*s*log2(e)

    v2f u[16], drv[16];
#pragma unroll
    for (int k = 0; k < 4; ++k) {
        const float4 xA = *reinterpret_cast<const float4*>(X    + baseA + k * 4);
        const float4 xB = *reinterpret_cast<const float4*>(X    + baseB + k * 4);
        const float4 pA = *reinterpret_cast<const float4*>(pred + baseA + k * 4);
        const float4 pB = *reinterpret_cast<const float4*>(pred + baseB + k * 4);
        const float4 b4 = *reinterpret_cast<const float4*>(bias + prow + k * 4);
        const float4 a4 = *reinterpret_cast<const float4*>(av   + prow + k * 4);
        const float xa[4] = {xA.x, xA.y, xA.z, xA.w};
        const float xb[4] = {xB.x, xB.y, xB.z, xB.w};
        const float pa[4] = {pA.x, pA.y, pA.z, pA.w};
        const float pb[4] = {pB.x, pB.y, pB.z, pB.w};
        const float bb[4] = {b4.x, b4.y, b4.z, b4.w};
        const float aa[4] = {a4.x, a4.y, a4.z, a4.w};
#pragma unroll
        for (int j = 0; j < 4; ++j) {
            const int c = k * 4 + j;
            const float ua = pa[j], ub = pb[j];
            const float fa = (ua == -1.0f) ? 0.0f : ua;   // u_fix
            const float fb = (ub == -1.0f) ? 0.0f : ub;
            drv[c].x = K * ((fa + bb[j]) + aa[j] * xa[j]);
            drv[c].y = K * ((fb + bb[j]) + aa[j] * xb[j]);
            u[c].x = ua;                                  // scan carry = raw pred
            u[c].y = ub;
        }
    }
    // w per row: boundary cols (0,15) share one value, interior cols another (K-prescaled)
    const float wbs = K * w[prow];
    const float was = K * w[prow + 1];
    const v2f w2b = {wbs, wbs};
    const v2f w2a = {was, was};

#pragma unroll 1
    for (int it = 0; it < LAYERS; ++it) {
        // streamed stencil+activation: 1-column delay so old u[c] survives for
        // column c+1's horizontal neighbor; caps ns liveness at 1 register pair.
        v2f uprev = u[0];                      // old u[c-1] carry
        {   // c = 0
            v2f ns = vert_add(u[1], u[0]);
            u[0] = act(ns, drv[0], w2b);
        }
#pragma unroll
        for (int c = 1; c < 15; ++c) {
            v2f ns = vert_add(uprev + u[c + 1], u[c]);
            uprev = u[c];
            u[c] = act(ns, drv[c], w2a);
        }
        {   // c = 15
            v2f ns = vert_add(uprev, u[15]);
            u[15] = act(ns, drv[15], w2b);
        }
    }

#pragma unroll
    for (int k = 0; k < 4; ++k) {
        if (act0) {
            float4 oA;
            oA.x = u[k * 4 + 0].x; oA.y = u[k * 4 + 1].x;
            oA.z = u[k * 4 + 2].x; oA.w = u[k * 4 + 3].x;
            *reinterpret_cast<float4*>(out + baseA + k * 4) = oA;
        }
        if (act1) {
            float4 oB;
            oB.x = u[k * 4 + 0].y; oB.y = u[k * 4 + 1].y;
            oB.z = u[k * 4 + 2].y; oB.w = u[k * 4 + 3].y;
            *reinterpret_cast<float4*>(out + baseB + k * 4) = oB;
        }
    }
}

} // namespace

extern "C" void kernel_launch(void* const* d_in, const int* in_sizes, int n_in,
                              void* d_out, int out_size, void* d_ws, size_t ws_size,
                              hipStream_t stream) {
    // setup_inputs order: X, pred, W_hidden, w, a, bias, scalar
    const float* X      = (const float*)d_in[0];
    const float* pred   = (const float*)d_in[1];
    // d_in[2] = W_hidden: fixed grid adjacency, hardcoded as the stencil
    const float* w      = (const float*)d_in[3];
    const float* av     = (const float*)d_in[4];
    const float* bias   = (const float*)d_in[5];
    const float* scalar = (const float*)d_in[6];
    float* out = (float*)d_out;

    const int nb = in_sizes[0] / HPIX;  // batch rows (32768)
    const int imgs_per_block = WAVES_PER_BLOCK * IMGS_PER_WAVE;
    const int blocks = (nb + imgs_per_block - 1) / imgs_per_block;

    pp_kernel<<<dim3(blocks), dim3(WAVES_PER_BLOCK * 64), 0, stream>>>(
        X, pred, w, av, bias, scalar, out, nb);
}

// Round 7
// 73.272 us; speedup vs baseline: 1.4644x; 1.4644x over previous
//
#include <hip/hip_runtime.h>

// RecurrentFixed_PredPrey: 30 iterations of u = tanh(scalar * (drive + w ⊙ N4-stencil(u)))
// on 32768 independent 16x16 images. W_hidden is the fixed grid adjacency -> stencil.
//
// R6 layout: 2 images per wave, 8 px per lane (scalar f32 code — R5's packing scalarized
// and collapsed occupancy; wave count is the lever, per R2/R4/R5 busy-cycle fits).
//   lane = (g = l>>5 image, rg = (l>>4)&1 row-strip, c = l&15 column)
//   lane owns rows {rg*8+k, k=0..7} of column c in registers u[0..7].
//   horizontal: DPP row_shr:1/row_shl:1 — each 16-lane DPP row IS one (g,rg) group,
//               bound_ctrl zeroes column edges for free.
//   vertical:   rows 1..6 in-register; strip boundary (rows 7<->8) via ONE ds_bpermute:
//               each lane publishes the row its partner (lane^16) needs.
//               image top/bottom edges are in-register zeros (no masks).
// Activation (R4 math, proven): tanh(s*v) = 1 - 2/(exp2(K*v)+1), K = 2*s*log2(e),
//   w/drive pre-scaled by K -> per px: fma, exp2, add, rcp, fma = 3 VALU + 2 trans.

namespace {

constexpr int HPIX   = 256;
constexpr int LAYERS = 30;
constexpr int WAVES_PER_BLOCK = 4;
constexpr int IMGS_PER_WAVE   = 2;

template <int CTRL>
__device__ __forceinline__ float dppf(float x) {
    // old = 0, bound_ctrl=1: out-of-row source lanes yield 0.0f (image column edge)
    int r = __builtin_amdgcn_update_dpp(0, __float_as_int(x), CTRL, 0xF, 0xF, true);
    return __int_as_float(r);
}

__global__ __launch_bounds__(WAVES_PER_BLOCK * 64)
void pp_kernel(const float* __restrict__ X, const float* __restrict__ pred,
               const float* __restrict__ w, const float* __restrict__ av,
               const float* __restrict__ bias, const float* __restrict__ scalar,
               float* __restrict__ out, int nb)
{
    const int lane = threadIdx.x & 63;
    const int wid  = blockIdx.x * WAVES_PER_BLOCK + (threadIdx.x >> 6);
    const int g    = lane >> 5;                 // image in wave: 0..1
    const int rg   = (lane >> 4) & 1;           // row strip: 0 -> rows 0..7, 1 -> 8..15
    const int c    = lane & 15;                 // column 0..15
    const int img  = wid * IMGS_PER_WAVE + g;
    const bool active = (img < nb);
    const int imgc = active ? img : 0;          // clamp for safe loads
    const int r0   = rg * 8;                    // first row of this lane's strip
    const size_t base = (size_t)imgc * HPIX + r0 * 16 + c;   // pixel (r0, c)

    const float s = scalar[0];
    const float K = 2.0f * s * 1.4426950408889634f;   // 2*s*log2(e)

    float u[8], drv[8];
#pragma unroll
    for (int k = 0; k < 8; ++k) {
        const int p = r0 * 16 + k * 16 + c;            // param index (row r0+k, col c)
        const float pr = pred[base + k * 16];
        const float x  = X[base + k * 16];
        const float fu = (pr == -1.0f) ? 0.0f : pr;    // u_fix
        drv[k] = K * ((fu + bias[p]) + av[p] * x);     // K-prescaled layer-invariant drive
        u[k]   = pr;                                   // scan carry = raw pred
    }
    // weights for this column: image row-edge rows (0/15) vs middle rows.
    // w[row0,c] == w[row15,c] by edge/corner symmetry.
    const float wEnd = K * w[c];          // row 0 (== row 15), col c
    const float wMid = K * w[16 + c];     // middle rows, col c
    const float w_k0 = rg ? wMid : wEnd;  // k=0 is image row 0 only when rg==0
    const float w_k7 = rg ? wEnd : wMid;  // k=7 is image row 15 only when rg==1

    const int partner_addr = (lane ^ 16) << 2;   // ds_bpermute byte address (hoisted)

#pragma unroll 1
    for (int it = 0; it < LAYERS; ++it) {
        // strip-boundary exchange: publish the row the partner strip needs
        // (rg0 partner needs our row7=u[7]; rg1 partner needs our row8=u[0])
        const float pub = rg ? u[0] : u[7];
        const float nbr = __int_as_float(
            __builtin_amdgcn_ds_bpermute(partner_addr, __float_as_int(pub)));
        const float tN = rg ? nbr : 0.0f;   // top neighbor of k=0 (0 at image top edge)
        const float bN = rg ? 0.0f : nbr;   // bottom neighbor of k=7 (0 at image bottom)

        // vertical neighbor sums (all old-u reads happen before any u update)
        float ns[8];
        ns[0] = tN + u[1];
        ns[7] = u[6] + bN;
#pragma unroll
        for (int k = 1; k < 7; ++k) ns[k] = u[k - 1] + u[k + 1];
        // horizontal via DPP (bound_ctrl zeroes column edges)
#pragma unroll
        for (int k = 0; k < 8; ++k)
            ns[k] = ns[k] + dppf<0x111>(u[k]) + dppf<0x101>(u[k]);
        // activation: u = 1 - 2/(exp2(m)+1), m = fma(w2, ns, drv2)
#pragma unroll
        for (int k = 0; k < 8; ++k) {
            const float wc = (k == 0) ? w_k0 : (k == 7) ? w_k7 : wMid;
            const float m  = __builtin_fmaf(wc, ns[k], drv[k]);
            const float e  = __builtin_amdgcn_exp2f(m);
            const float rd = __builtin_amdgcn_rcpf(e + 1.0f);
            u[k] = __builtin_fmaf(rd, -2.0f, 1.0f);
        }
    }

    if (active) {
#pragma unroll
        for (int k = 0; k < 8; ++k)
            out[base + k * 16] = u[k];
    }
}

} // namespace

extern "C" void kernel_launch(void* const* d_in, const int* in_sizes, int n_in,
                              void* d_out, int out_size, void* d_ws, size_t ws_size,
                              hipStream_t stream) {
    // setup_inputs order: X, pred, W_hidden, w, a, bias, scalar
    const float* X      = (const float*)d_in[0];
    const float* pred   = (const float*)d_in[1];
    // d_in[2] = W_hidden: fixed grid adjacency, hardcoded as the stencil
    const float* w      = (const float*)d_in[3];
    const float* av     = (const float*)d_in[4];
    const float* bias   = (const float*)d_in[5];
    const float* scalar = (const float*)d_in[6];
    float* out = (float*)d_out;

    const int nb = in_sizes[0] / HPIX;  // batch rows (32768)
    const int imgs_per_block = WAVES_PER_BLOCK * IMGS_PER_WAVE;   // 8
    const int blocks = (nb + imgs_per_block - 1) / imgs_per_block; // 4096

    pp_kernel<<<dim3(blocks), dim3(WAVES_PER_BLOCK * 64), 0, stream>>>(
        X, pred, w, av, bias, scalar, out, nb);
}